// Round 7
// baseline (1338.400 us; speedup 1.0000x reference)
//
#include <hip/hip_runtime.h>
#include <hip/hip_cooperative_groups.h>
#include <stdint.h>

namespace cg = cooperative_groups;

// Problem constants
#define NGRAPH 1024
#define DFEAT  256
#define KATOM  64
#define KBOND  128
#define SMEM_BYTES 158720

typedef __attribute__((ext_vector_type(4))) float accv_t;
typedef __attribute__((ext_vector_type(8))) short bfrag_t;
typedef __attribute__((ext_vector_type(4))) unsigned short upk4_t;
typedef __attribute__((ext_vector_type(8))) unsigned short upk8_t;

__device__ __forceinline__ unsigned short f2bf(float f) {
    union { float f; unsigned int u; } v; v.f = f;
    return (unsigned short)((v.u + 0x7FFFu + ((v.u >> 16) & 1u)) >> 16);
}
__device__ __forceinline__ float bf2f(unsigned short h) {
    union { unsigned int u; float f; } v; v.u = ((unsigned int)h) << 16;
    return v.f;
}
__device__ __forceinline__ unsigned int pack2(float a, float b) {
    return (unsigned int)f2bf(a) | ((unsigned int)f2bf(b) << 16);
}
__device__ __forceinline__ float lo2f(unsigned int u) {
    union { unsigned int x; float f; } v; v.x = u << 16; return v.f;
}
__device__ __forceinline__ float hi2f(unsigned int u) {
    union { unsigned int x; float f; } v; v.x = u & 0xFFFF0000u; return v.f;
}
__device__ __forceinline__ float sigm(float x) { return 1.0f / (1.0f + __expf(-x)); }
__device__ __forceinline__ float tanh_f(float x) {
    float e = __expf(2.0f * x);
    return 1.0f - 2.0f / (e + 1.0f);
}

// ---------------------------------------------------------------------------
// Prep: Wc[set][n][k] (bf16), bsum = b_ih + b_hh. set0 = atom, set1 = bond.
// ---------------------------------------------------------------------------
__global__ __launch_bounds__(512) void k_prep(
    const float* __restrict__ WihA, const float* __restrict__ WhhA,
    const float* __restrict__ bihA, const float* __restrict__ bhhA,
    const float* __restrict__ WihB, const float* __restrict__ WhhB,
    const float* __restrict__ bihB, const float* __restrict__ bhhB,
    unsigned short* __restrict__ Wc, float* __restrict__ bsum)
{
    int bid = blockIdx.x;
    int set = bid >> 10;
    int n   = bid & 1023;
    int k   = threadIdx.x;
    const float* Wih = set ? WihB : WihA;
    const float* Whh = set ? WhhB : WhhA;
    float w = Wih[(size_t)n * 512 + k];
    if (k < 256) w += Whh[(size_t)n * 256 + k];
    Wc[((size_t)(set << 10) + n) * 512 + k] = f2bf(w);
    if (k == 0) {
        const float* bih = set ? bihB : bihA;
        const float* bhh = set ? bhhB : bhhA;
        bsum[(set << 10) + n] = bih[n] + bhh[n];
    }
}

// ---------------------------------------------------------------------------
// Persistent cooperative kernel: 256 blocks x 512 threads, 1 block/CU.
// Block b owns atom graphs 4b..4b+3 (LDS-resident feat, 128 KB) and bond
// graphs 4b..4b+3 (VGPR-resident feat: wave w = graph 4b+(w>>1), half w&1;
// lane (g,s) holds 16 nodes {g+4j} x dims [16s,16s+16) as packed bf16 pairs).
// Per iteration: [GEMM tiles -> grid.sync] -> LSTM (c,q in LDS) -> attention
// from regs/LDS -> grid.sync. feat read from HBM exactly once.
// ---------------------------------------------------------------------------
__global__ __launch_bounds__(512, 2) void k_persist(
    const float* __restrict__ featA, const float* __restrict__ featB,
    const unsigned short* __restrict__ Wc, const float* __restrict__ bsum,
    const float* __restrict__ fg, float* __restrict__ gates,
    float* __restrict__ hr, float* __restrict__ out)
{
    extern __shared__ char smem[];
    unsigned int*   alds  = (unsigned int*)smem;                  // 131072 B atom feat
    char*           pool  = smem + 131072;                        // 15360 B union
    unsigned short* sA    = (unsigned short*)pool;                // gemm A stage 128x40
    unsigned short* sB    = (unsigned short*)(pool + 10240);      // gemm B stage 64x40
    float*          rpart = (float*)pool;                         // [8][256] attn partials
    float*          csbuf = (float*)(pool + 8192);                // [8][2] (M,S)
    float*          c_lds = (float*)(smem + 146432);              // [8][256] c state
    unsigned int*   qpk   = (unsigned int*)(smem + 154624);       // [8][128] q bf16 pairs

    const int b    = blockIdx.x;
    const int t    = threadIdx.x;
    const int w    = t >> 6;
    const int lane = t & 63;
    const int g    = lane >> 4;
    const int s    = lane & 15;
    const int lg   = w >> 1;       // local graph 0..3
    const int hv   = w & 1;        // node half
    const int l15  = lane & 15;
    const int khalf = (lane >> 4) * 8;
    const int r4    = (lane >> 4) * 4;

    // ---------------- load bond feat -> VGPR (packed bf16) ----------------
    unsigned int fr[16][8];
    {
        const float* src = featB + (((size_t)(4 * b + lg) * 128) + (size_t)hv * 64) * 256;
        #pragma unroll
        for (int j = 0; j < 16; ++j) {
            const float* p = src + (size_t)(4 * j + g) * 256 + s * 16;
            #pragma unroll
            for (int q4 = 0; q4 < 4; ++q4) {
                float4 v = *(const float4*)(p + q4 * 4);
                fr[j][q4 * 2]     = pack2(v.x, v.y);
                fr[j][q4 * 2 + 1] = pack2(v.z, v.w);
            }
        }
    }
    // ---------------- load atom feat -> LDS (packed bf16) ----------------
    {
        const float* src = featA + (size_t)(4 * b) * 64 * 256;
        #pragma unroll
        for (int i = 0; i < 32; ++i) {
            int f4 = t + 512 * i;                       // 16384 float4 total
            float4 v = *(const float4*)(src + (size_t)f4 * 4);
            alds[f4 * 2]     = pack2(v.x, v.y);
            alds[f4 * 2 + 1] = pack2(v.z, v.w);
        }
    }
    __syncthreads();

    for (int it = 0; it < 6; ++it) {
        if (it > 0) {
            // ================= GEMM phase: 256 tiles of 128x64, K=512 ======
            const int mtile = b >> 4, ntile = b & 15;
            const int mbase = mtile * 128, nbase = ntile * 64;
            const int gset  = (mtile >= 8);
            accv_t acc[2][2];
            #pragma unroll
            for (int i = 0; i < 2; ++i)
                #pragma unroll
                for (int j = 0; j < 2; ++j)
                    acc[i][j] = (accv_t){0.f, 0.f, 0.f, 0.f};
            for (int k0 = 0; k0 < 512; k0 += 32) {
                #pragma unroll
                for (int i = 0; i < 2; ++i) {
                    int idx = t + 512 * i;              // 1024 float4
                    int row = idx >> 3;
                    int kc  = (idx & 7) * 4;
                    float4 a = *(const float4*)&hr[(size_t)(mbase + row) * 512 + k0 + kc];
                    *(upk4_t*)&sA[row * 40 + kc] =
                        (upk4_t){f2bf(a.x), f2bf(a.y), f2bf(a.z), f2bf(a.w)};
                }
                if (t < 256) {                          // 256 ushort8
                    int row = t >> 2;
                    int kc  = (t & 3) * 8;
                    *(upk8_t*)&sB[row * 40 + kc] =
                        *(const upk8_t*)&Wc[((size_t)(gset << 10) + nbase + row) * 512 + k0 + kc];
                }
                __syncthreads();
                const int wr = w >> 1, wcq = w & 1;
                bfrag_t a_f[2], b_f[2];
                #pragma unroll
                for (int i = 0; i < 2; ++i)
                    a_f[i] = *(const bfrag_t*)&sA[(wr * 32 + i * 16 + l15) * 40 + khalf];
                #pragma unroll
                for (int j = 0; j < 2; ++j)
                    b_f[j] = *(const bfrag_t*)&sB[(wcq * 32 + j * 16 + l15) * 40 + khalf];
                #pragma unroll
                for (int i = 0; i < 2; ++i)
                    #pragma unroll
                    for (int j = 0; j < 2; ++j)
                        acc[i][j] = __builtin_amdgcn_mfma_f32_16x16x32_bf16(a_f[i], b_f[j], acc[i][j], 0, 0, 0);
                __syncthreads();
            }
            {
                const int wr = w >> 1, wcq = w & 1;
                #pragma unroll
                for (int i = 0; i < 2; ++i) {
                    #pragma unroll
                    for (int j = 0; j < 2; ++j) {
                        int col = nbase + wcq * 32 + j * 16 + l15;
                        float bs = bsum[(gset << 10) + col];
                        #pragma unroll
                        for (int v = 0; v < 4; ++v) {
                            int row = mbase + wr * 32 + i * 16 + r4 + v;
                            gates[(size_t)row * 1024 + col] = acc[i][j][v] + bs;
                        }
                    }
                }
            }
            __threadfence();
            cg::this_grid().sync();
        }

        // ================= LSTM phase (block-local graphs) =================
        #pragma unroll
        for (int p = 0; p < 2; ++p) {
            int idx = t + 512 * p;          // 0..1023 = 8 graphs x 128 pairs
            int lgx = idx >> 7;
            int pr  = idx & 127;
            int d0  = pr * 2;
            int set = (lgx >= 4);
            int row = set ? (1024 + 4 * b + (lgx - 4)) : (4 * b + lgx);
            float gi0, gi1, gf0, gf1, gg0, gg1, go0, go1, c0, c1;
            if (it == 0) {
                const float* bs = bsum + (set << 10);
                gi0 = bs[d0];       gi1 = bs[d0 + 1];
                gf0 = bs[256 + d0]; gf1 = bs[256 + d0 + 1];
                gg0 = bs[512 + d0]; gg1 = bs[512 + d0 + 1];
                go0 = bs[768 + d0]; go1 = bs[768 + d0 + 1];
                c0 = 0.f; c1 = 0.f;
            } else {
                const float* gp = gates + (size_t)row * 1024;
                float2 a0 = *(const float2*)(gp + d0);
                float2 a1 = *(const float2*)(gp + 256 + d0);
                float2 a2 = *(const float2*)(gp + 512 + d0);
                float2 a3 = *(const float2*)(gp + 768 + d0);
                gi0 = a0.x; gi1 = a0.y; gf0 = a1.x; gf1 = a1.y;
                gg0 = a2.x; gg1 = a2.y; go0 = a3.x; go1 = a3.y;
                c0 = c_lds[lgx * 256 + d0];
                c1 = c_lds[lgx * 256 + d0 + 1];
            }
            float cn0 = sigm(gf0) * c0 + sigm(gi0) * tanh_f(gg0);
            float cn1 = sigm(gf1) * c1 + sigm(gi1) * tanh_f(gg1);
            float h0 = sigm(go0) * tanh_f(cn0);
            float h1 = sigm(go1) * tanh_f(cn1);
            c_lds[lgx * 256 + d0]     = cn0;
            c_lds[lgx * 256 + d0 + 1] = cn1;
            qpk[lgx * 128 + pr] = pack2(h0, h1);
            if (it == 5) {
                *(float2*)&out[(size_t)(4 * b + (lgx & 3)) * 1152 + (set ? 512 : 0) + d0] =
                    make_float2(h0, h1);
            } else {
                *(float2*)&hr[(size_t)row * 512 + d0] = make_float2(h0, h1);
            }
        }
        __syncthreads();

        // ================= ATTN: bond (feat in registers) ==================
        {
            float qf[16];
            #pragma unroll
            for (int m = 0; m < 8; ++m) {
                unsigned int u = qpk[(4 + lg) * 128 + s * 8 + m];
                qf[2 * m] = lo2f(u); qf[2 * m + 1] = hi2f(u);
            }
            float e[16];
            #pragma unroll
            for (int j = 0; j < 16; ++j) {
                float a = 0.f;
                #pragma unroll
                for (int m = 0; m < 8; ++m)
                    a += lo2f(fr[j][m]) * qf[2 * m] + hi2f(fr[j][m]) * qf[2 * m + 1];
                a += __shfl_xor(a, 1); a += __shfl_xor(a, 2);
                a += __shfl_xor(a, 4); a += __shfl_xor(a, 8);
                e[j] = a;
            }
            float M = e[0];
            #pragma unroll
            for (int j = 1; j < 16; ++j) M = fmaxf(M, e[j]);
            M = fmaxf(M, __shfl_xor(M, 16));
            M = fmaxf(M, __shfl_xor(M, 32));
            float S = 0.f;
            #pragma unroll
            for (int j = 0; j < 16; ++j) { e[j] = __expf(e[j] - M); S += e[j]; }
            S += __shfl_xor(S, 16); S += __shfl_xor(S, 32);
            float r[16];
            #pragma unroll
            for (int m = 0; m < 16; ++m) r[m] = 0.f;
            #pragma unroll
            for (int j = 0; j < 16; ++j) {
                #pragma unroll
                for (int m = 0; m < 8; ++m) {
                    r[2 * m]     += e[j] * lo2f(fr[j][m]);
                    r[2 * m + 1] += e[j] * hi2f(fr[j][m]);
                }
            }
            #pragma unroll
            for (int m = 0; m < 16; ++m) {
                r[m] += __shfl_xor(r[m], 16);
                r[m] += __shfl_xor(r[m], 32);
            }
            if (g == 0) {
                #pragma unroll
                for (int m = 0; m < 16; m += 4)
                    *(float4*)&rpart[(hv * 4 + lg) * 256 + s * 16 + m] =
                        make_float4(r[m], r[m + 1], r[m + 2], r[m + 3]);
            }
            if (lane == 0) { csbuf[(hv * 4 + lg) * 2] = M; csbuf[(hv * 4 + lg) * 2 + 1] = S; }
        }
        __syncthreads();
        if (hv == 0) {   // bond combine: waves 0,2,4,6 merge graph lg's 2 halves
            float M0 = csbuf[lg * 2],       S0 = csbuf[lg * 2 + 1];
            float M1 = csbuf[(4 + lg) * 2], S1 = csbuf[(4 + lg) * 2 + 1];
            float Mx = fmaxf(M0, M1);
            float f0 = __expf(M0 - Mx), f1 = __expf(M1 - Mx);
            float Sx = S0 * f0 + S1 * f1;
            int d4 = lane * 4;
            float4 p0 = *(const float4*)&rpart[lg * 256 + d4];
            float4 p1 = *(const float4*)&rpart[(4 + lg) * 256 + d4];
            float4 rv = make_float4((p0.x * f0 + p1.x * f1) / Sx, (p0.y * f0 + p1.y * f1) / Sx,
                                    (p0.z * f0 + p1.z * f1) / Sx, (p0.w * f0 + p1.w * f1) / Sx);
            if (it == 5) *(float4*)&out[(size_t)(4 * b + lg) * 1152 + 768 + d4] = rv;
            else         *(float4*)&hr[(size_t)(1024 + 4 * b + lg) * 512 + 256 + d4] = rv;
        }
        __syncthreads();

        // ================= ATTN: atom (feat in LDS) ========================
        {
            float qf[16];
            #pragma unroll
            for (int m = 0; m < 8; ++m) {
                unsigned int u = qpk[lg * 128 + s * 8 + m];
                qf[2 * m] = lo2f(u); qf[2 * m + 1] = hi2f(u);
            }
            float e[8];
            #pragma unroll
            for (int j = 0; j < 8; ++j) {
                int node = hv * 32 + g + 4 * j;
                const unsigned int* xp = &alds[(size_t)(lg * 64 + node) * 128 + s * 8];
                float a = 0.f;
                #pragma unroll
                for (int m = 0; m < 8; ++m)
                    a += lo2f(xp[m]) * qf[2 * m] + hi2f(xp[m]) * qf[2 * m + 1];
                a += __shfl_xor(a, 1); a += __shfl_xor(a, 2);
                a += __shfl_xor(a, 4); a += __shfl_xor(a, 8);
                e[j] = a;
            }
            float M = e[0];
            #pragma unroll
            for (int j = 1; j < 8; ++j) M = fmaxf(M, e[j]);
            M = fmaxf(M, __shfl_xor(M, 16));
            M = fmaxf(M, __shfl_xor(M, 32));
            float S = 0.f;
            #pragma unroll
            for (int j = 0; j < 8; ++j) { e[j] = __expf(e[j] - M); S += e[j]; }
            S += __shfl_xor(S, 16); S += __shfl_xor(S, 32);
            float r[16];
            #pragma unroll
            for (int m = 0; m < 16; ++m) r[m] = 0.f;
            #pragma unroll
            for (int j = 0; j < 8; ++j) {
                int node = hv * 32 + g + 4 * j;
                const unsigned int* xp = &alds[(size_t)(lg * 64 + node) * 128 + s * 8];
                #pragma unroll
                for (int m = 0; m < 8; ++m) {
                    r[2 * m]     += e[j] * lo2f(xp[m]);
                    r[2 * m + 1] += e[j] * hi2f(xp[m]);
                }
            }
            #pragma unroll
            for (int m = 0; m < 16; ++m) {
                r[m] += __shfl_xor(r[m], 16);
                r[m] += __shfl_xor(r[m], 32);
            }
            if (g == 0) {
                #pragma unroll
                for (int m = 0; m < 16; m += 4)
                    *(float4*)&rpart[(hv * 4 + lg) * 256 + s * 16 + m] =
                        make_float4(r[m], r[m + 1], r[m + 2], r[m + 3]);
            }
            if (lane == 0) { csbuf[(hv * 4 + lg) * 2] = M; csbuf[(hv * 4 + lg) * 2 + 1] = S; }
        }
        __syncthreads();
        if (hv == 0) {   // atom combine
            float M0 = csbuf[lg * 2],       S0 = csbuf[lg * 2 + 1];
            float M1 = csbuf[(4 + lg) * 2], S1 = csbuf[(4 + lg) * 2 + 1];
            float Mx = fmaxf(M0, M1);
            float f0 = __expf(M0 - Mx), f1 = __expf(M1 - Mx);
            float Sx = S0 * f0 + S1 * f1;
            int d4 = lane * 4;
            float4 p0 = *(const float4*)&rpart[lg * 256 + d4];
            float4 p1 = *(const float4*)&rpart[(4 + lg) * 256 + d4];
            float4 rv = make_float4((p0.x * f0 + p1.x * f1) / Sx, (p0.y * f0 + p1.y * f1) / Sx,
                                    (p0.z * f0 + p1.z * f1) / Sx, (p0.w * f0 + p1.w * f1) / Sx);
            if (it == 5) *(float4*)&out[(size_t)(4 * b + lg) * 1152 + 256 + d4] = rv;
            else         *(float4*)&hr[(size_t)(4 * b + lg) * 512 + 256 + d4] = rv;
        }
        __syncthreads();
        if (it < 5) { __threadfence(); cg::this_grid().sync(); }
    }

    // ---------------- feat_global tail ----------------
    {
        int gr = t >> 7, c = t & 127;
        out[(size_t)(4 * b + gr) * 1152 + 1024 + c] = fg[(size_t)(4 * b + gr) * 128 + c];
    }
}

// ===========================================================================
// Fallback pipeline (R6, proven): used only if cooperative launch fails.
// ===========================================================================
__global__ __launch_bounds__(256) void k_cvt(
    const float* __restrict__ fA, const float* __restrict__ fB,
    unsigned short* __restrict__ oA, unsigned short* __restrict__ oB)
{
    int tid = blockIdx.x * 256 + threadIdx.x;
    const int T = 2048 * 256;
    #pragma unroll 2
    for (int i = tid; i < 4194304; i += T) {
        accv_t v = __builtin_nontemporal_load((const accv_t*)fA + i);
        upk4_t u; u[0]=f2bf(v[0]); u[1]=f2bf(v[1]); u[2]=f2bf(v[2]); u[3]=f2bf(v[3]);
        *((upk4_t*)oA + i) = u;
    }
    #pragma unroll 2
    for (int i = tid; i < 8388608; i += T) {
        accv_t v = __builtin_nontemporal_load((const accv_t*)fB + i);
        upk4_t u; u[0]=f2bf(v[0]); u[1]=f2bf(v[1]); u[2]=f2bf(v[2]); u[3]=f2bf(v[3]);
        *((upk4_t*)oB + i) = u;
    }
}

__global__ __launch_bounds__(256) void k_gemm(
    const float* __restrict__ hr, const unsigned short* __restrict__ Wc,
    const float* __restrict__ bsum, float* __restrict__ gates)
{
    __shared__ unsigned short sA[64 * 40];
    __shared__ unsigned short sB[128 * 40];
    int set   = blockIdx.x >> 7;
    int qq    = blockIdx.x & 127;
    int mbase = (qq >> 3) * 64;
    int nbase = (qq & 7) * 128;
    int t     = threadIdx.x;
    int lane  = t & 63;
    int w     = t >> 6;
    int wrow  = (w >> 1) * 32;
    int wcol  = (w & 1) * 64;
    int l15   = lane & 15;
    int khalf = (lane >> 4) * 8;
    const float* A           = hr + (size_t)(set << 10) * 512;
    const unsigned short* Bm = Wc + (size_t)(set << 10) * 512;
    accv_t acc[2][4];
    #pragma unroll
    for (int i = 0; i < 2; ++i)
        #pragma unroll
        for (int j = 0; j < 4; ++j)
            acc[i][j] = (accv_t){0.f, 0.f, 0.f, 0.f};
    for (int k0 = 0; k0 < 512; k0 += 32) {
        #pragma unroll
        for (int i = 0; i < 2; ++i) {
            int idx4 = t + 256 * i;
            int row  = idx4 >> 3;
            int kc   = (idx4 & 7) * 4;
            const float4 a = *(const float4*)&A[(size_t)(mbase + row) * 512 + k0 + kc];
            upk4_t u; u[0]=f2bf(a.x); u[1]=f2bf(a.y); u[2]=f2bf(a.z); u[3]=f2bf(a.w);
            *(upk4_t*)&sA[row * 40 + kc] = u;
        }
        #pragma unroll
        for (int i = 0; i < 2; ++i) {
            int idx8 = t + 256 * i;
            int row  = idx8 >> 2;
            int kc   = (idx8 & 3) * 8;
            *(upk8_t*)&sB[row * 40 + kc] =
                *(const upk8_t*)&Bm[(size_t)(nbase + row) * 512 + k0 + kc];
        }
        __syncthreads();
        bfrag_t a_f[2], b_f[4];
        #pragma unroll
        for (int i = 0; i < 2; ++i)
            a_f[i] = *(const bfrag_t*)&sA[(wrow + i * 16 + l15) * 40 + khalf];
        #pragma unroll
        for (int j = 0; j < 4; ++j)
            b_f[j] = *(const bfrag_t*)&sB[(wcol + j * 16 + l15) * 40 + khalf];
        #pragma unroll
        for (int i = 0; i < 2; ++i)
            #pragma unroll
            for (int j = 0; j < 4; ++j)
                acc[i][j] = __builtin_amdgcn_mfma_f32_16x16x32_bf16(a_f[i], b_f[j], acc[i][j], 0, 0, 0);
        __syncthreads();
    }
    int r4 = (lane >> 4) * 4;
    #pragma unroll
    for (int i = 0; i < 2; ++i) {
        #pragma unroll
        for (int j = 0; j < 4; ++j) {
            int col  = nbase + wcol + j * 16 + l15;
            float bs = bsum[(set << 10) + col];
            #pragma unroll
            for (int v = 0; v < 4; ++v) {
                int row = mbase + wrow + i * 16 + r4 + v;
                gates[((size_t)(set << 10) + row) * 1024 + col] = acc[i][j][v] + bs;
            }
        }
    }
}

template <int NQ>
__device__ __forceinline__ void attn_core(
    const unsigned short* __restrict__ fb, const float* __restrict__ qv,
    int s, float* __restrict__ rrow, float& C, float& sacc)
{
    upk8_t h0[NQ], h1[NQ];
    #pragma unroll
    for (int qd = 0; qd < NQ; ++qd) {
        const unsigned short* p = fb + (size_t)qd * 1024;
        h0[qd] = *(const upk8_t*)(p);
        h1[qd] = *(const upk8_t*)(p + 128);
    }
    float qr[16];
    #pragma unroll
    for (int j = 0; j < 8; ++j) { qr[j] = qv[s*8 + j]; qr[8+j] = qv[128 + s*8 + j]; }
    float r[16];
    #pragma unroll
    for (int j = 0; j < 16; ++j) r[j] = 0.0f;
    #pragma unroll
    for (int qd = 0; qd < NQ; ++qd) {
        float x[16];
        #pragma unroll
        for (int j = 0; j < 8; ++j) { x[j] = bf2f(h0[qd][j]); x[8+j] = bf2f(h1[qd][j]); }
        float e = 0.0f;
        #pragma unroll
        for (int j = 0; j < 16; ++j) e += x[j] * qr[j];
        e += __shfl_xor(e, 1); e += __shfl_xor(e, 2);
        e += __shfl_xor(e, 4); e += __shfl_xor(e, 8);
        float w = (qd == 0) ? 1.0f : __expf(e - C);
        if (qd == 0) C = e;
        sacc += w;
        #pragma unroll
        for (int j = 0; j < 16; ++j) r[j] += w * x[j];
    }
    #pragma unroll
    for (int j = 0; j < 8; j += 4) {
        *(float4*)&rrow[s*8 + j]       = *(float4*)&r[j];
        *(float4*)&rrow[128 + s*8 + j] = *(float4*)&r[8+j];
    }
}

template <int MODE, bool LAST>
__global__ __launch_bounds__(256) void k_attn(
    const float* __restrict__ featA, const float* __restrict__ featB,
    const unsigned short* __restrict__ fbfA, const unsigned short* __restrict__ fbfB,
    const float* __restrict__ gates, const float* __restrict__ bsum,
    float* __restrict__ hr, float* __restrict__ cst,
    const float* __restrict__ fgp, float* __restrict__ outp, int iter)
{
    __shared__ float qv[256];
    __shared__ float sw_s[16], cw_s[16];
    __shared__ float racc_s[16][260];
    int bid = blockIdx.x;
    int set = (bid < 1024) ? 1 : 0;
    int b   = bid & 1023;
    int K   = set ? KBOND : KATOM;
    int t = threadIdx.x;
    size_t sb = (size_t)(set << 10) + b;
    size_t ob = (size_t)b * 1152 + (set ? 512 : 0);
    {
        int d = t;
        float gi, gf, gg, go, cold;
        if (iter == 0) {
            gi = bsum[(set << 10) + d];
            gf = bsum[(set << 10) + 256 + d];
            gg = bsum[(set << 10) + 512 + d];
            go = bsum[(set << 10) + 768 + d];
            cold = 0.0f;
        } else {
            const float* gp = gates + sb * 1024;
            gi = gp[d]; gf = gp[256 + d]; gg = gp[512 + d]; go = gp[768 + d];
            cold = cst[sb * 256 + d];
        }
        float cn = sigm(gf) * cold + sigm(gi) * tanh_f(gg);
        float h  = sigm(go) * tanh_f(cn);
        if (LAST) { outp[ob + d] = h; }
        else      { cst[sb * 256 + d] = cn; hr[sb * 512 + d] = h; }
        qv[d] = h;
    }
    __syncthreads();
    int lane = t & 63;
    int wv   = t >> 6;
    int g    = lane >> 4;
    int s    = lane & 15;
    int npw  = K >> 2;
    int nq   = npw >> 2;
    int node0 = wv * npw + g;
    float C = 0.0f, sacc = 0.0f;
    int pid = (wv << 2) | g;
    if (MODE == 1) {
        const unsigned short* fb = (set ? fbfB : fbfA)
                                 + ((size_t)b * K + node0) * 256 + s * 8;
        if (set) attn_core<8>(fb, qv, s, racc_s[pid], C, sacc);
        else     attn_core<4>(fb, qv, s, racc_s[pid], C, sacc);
    } else {
        const float* feat = set ? featB : featA;
        const float* fb = feat + ((size_t)b * K + node0) * 256 + s * 4;
        float4 q0 = *(const float4*)&qv[s*4];
        float4 q1 = *(const float4*)&qv[64  + s*4];
        float4 q2 = *(const float4*)&qv[128 + s*4];
        float4 q3 = *(const float4*)&qv[192 + s*4];
        float4 r0 = make_float4(0.f,0.f,0.f,0.f), r1 = r0, r2 = r0, r3 = r0;
        #pragma unroll 2
        for (int qd = 0; qd < nq; ++qd) {
            const float* p = fb + (size_t)qd * 1024;
            float4 x0 = *(const float4*)(p);
            float4 x1 = *(const float4*)(p + 64);
            float4 x2 = *(const float4*)(p + 128);
            float4 x3 = *(const float4*)(p + 192);
            float e = x0.x*q0.x + x0.y*q0.y + x0.z*q0.z + x0.w*q0.w
                    + x1.x*q1.x + x1.y*q1.y + x1.z*q1.z + x1.w*q1.w
                    + x2.x*q2.x + x2.y*q2.y + x2.z*q2.z + x2.w*q2.w
                    + x3.x*q3.x + x3.y*q3.y + x3.z*q3.z + x3.w*q3.w;
            e += __shfl_xor(e, 1); e += __shfl_xor(e, 2);
            e += __shfl_xor(e, 4); e += __shfl_xor(e, 8);
            float w = (qd == 0) ? 1.0f : __expf(e - C);
            if (qd == 0) C = e;
            sacc += w;
            r0.x += w*x0.x; r0.y += w*x0.y; r0.z += w*x0.z; r0.w += w*x0.w;
            r1.x += w*x1.x; r1.y += w*x1.y; r1.z += w*x1.z; r1.w += w*x1.w;
            r2.x += w*x2.x; r2.y += w*x2.y; r2.z += w*x2.z; r2.w += w*x2.w;
            r3.x += w*x3.x; r3.y += w*x3.y; r3.z += w*x3.z; r3.w += w*x3.w;
        }
        *(float4*)&racc_s[pid][s*4]       = r0;
        *(float4*)&racc_s[pid][64  + s*4] = r1;
        *(float4*)&racc_s[pid][128 + s*4] = r2;
        *(float4*)&racc_s[pid][192 + s*4] = r3;
    }
    if (s == 0) { sw_s[pid] = sacc; cw_s[pid] = C; }
    __syncthreads();
    {
        float Cm = cw_s[0];
        #pragma unroll
        for (int p2 = 1; p2 < 16; ++p2) Cm = fmaxf(Cm, cw_s[p2]);
        float S = 0.0f, r = 0.0f;
        #pragma unroll
        for (int p2 = 0; p2 < 16; ++p2) {
            float f = __expf(cw_s[p2] - Cm);
            S += sw_s[p2] * f;
            r += racc_s[p2][t] * f;
        }
        float rv = r / S;
        if (LAST) {
            outp[ob + 256 + t] = rv;
            if (set && t < 128)
                outp[(size_t)b * 1152 + 1024 + t] = fgp[(size_t)b * 128 + t];
        } else {
            hr[sb * 512 + 256 + t] = rv;
        }
    }
}

extern "C" void kernel_launch(void* const* d_in, const int* in_sizes, int n_in,
                              void* d_out, int out_size, void* d_ws, size_t ws_size,
                              hipStream_t stream) {
    const float* feat_atom   = (const float*)d_in[0];
    const float* feat_bond   = (const float*)d_in[2];
    const float* feat_global = (const float*)d_in[4];
    const float* WihA = (const float*)d_in[5];
    const float* WhhA = (const float*)d_in[6];
    const float* bihA = (const float*)d_in[7];
    const float* bhhA = (const float*)d_in[8];
    const float* WihB = (const float*)d_in[9];
    const float* WhhB = (const float*)d_in[10];
    const float* bihB = (const float*)d_in[11];
    const float* bhhB = (const float*)d_in[12];
    float* out = (float*)d_out;

    char* ws = (char*)d_ws;
    unsigned short* Wc = (unsigned short*)(ws + 0);           // 2 MB
    float* bsum  = (float*)(ws + 2097152);                    // 8 KB
    float* gates = (float*)(ws + 2105344);                    // 8 MB
    float* hr    = (float*)(ws + 10493952);                   // 4 MB
    float* cst   = (float*)(ws + 14688256);                   // 2 MB (fallback)
    unsigned short* fbfA = (unsigned short*)(ws + 16785408);  // 32 MB (fallback)
    unsigned short* fbfB = (unsigned short*)(ws + 50339840);  // 64 MB (fallback)
    const size_t WS_FALLBACK = 50339840 + 67108864;
    (void)in_sizes; (void)n_in; (void)out_size;

    k_prep<<<2048, 512, 0, stream>>>(WihA, WhhA, bihA, bhhA,
                                     WihB, WhhB, bihB, bhhB, Wc, bsum);

    bool coop_ok = false;
    {
        hipError_t ea = hipFuncSetAttribute((const void*)k_persist,
            hipFuncAttributeMaxDynamicSharedMemorySize, SMEM_BYTES);
        if (ea == hipSuccess) {
            void* args[] = { (void*)&feat_atom, (void*)&feat_bond, (void*)&Wc,
                             (void*)&bsum, (void*)&feat_global, (void*)&gates,
                             (void*)&hr, (void*)&out };
            hipError_t eb = hipLaunchCooperativeKernel((const void*)k_persist,
                dim3(256), dim3(512), args, (unsigned int)SMEM_BYTES, stream);
            coop_ok = (eb == hipSuccess);
        }
    }
    if (!coop_ok) {
        bool bf = (ws_size >= WS_FALLBACK);
        if (bf) {
            k_cvt<<<2048, 256, 0, stream>>>(feat_atom, feat_bond, fbfA, fbfB);
            k_attn<1, false><<<2048, 256, 0, stream>>>(feat_atom, feat_bond, fbfA, fbfB,
                                                       gates, bsum, hr, cst,
                                                       feat_global, out, 0);
            for (int it = 1; it < 5; ++it) {
                k_gemm<<<256, 256, 0, stream>>>(hr, Wc, bsum, gates);
                k_attn<1, false><<<2048, 256, 0, stream>>>(feat_atom, feat_bond, fbfA, fbfB,
                                                           gates, bsum, hr, cst,
                                                           feat_global, out, it);
            }
            k_gemm<<<256, 256, 0, stream>>>(hr, Wc, bsum, gates);
            k_attn<1, true><<<2048, 256, 0, stream>>>(feat_atom, feat_bond, fbfA, fbfB,
                                                      gates, bsum, hr, cst,
                                                      feat_global, out, 5);
        } else {
            k_attn<2, false><<<2048, 256, 0, stream>>>(feat_atom, feat_bond, 0, 0,
                                                       gates, bsum, hr, cst,
                                                       feat_global, out, 0);
            for (int it = 1; it < 5; ++it) {
                k_gemm<<<256, 256, 0, stream>>>(hr, Wc, bsum, gates);
                k_attn<2, false><<<2048, 256, 0, stream>>>(feat_atom, feat_bond, 0, 0,
                                                           gates, bsum, hr, cst,
                                                           feat_global, out, it);
            }
            k_gemm<<<256, 256, 0, stream>>>(hr, Wc, bsum, gates);
            k_attn<2, true><<<2048, 256, 0, stream>>>(feat_atom, feat_bond, 0, 0,
                                                      gates, bsum, hr, cst,
                                                      feat_global, out, 5);
        }
    }
}

// Round 9
// 223.326 us; speedup vs baseline: 5.9930x; 5.9930x over previous
//
#include <hip/hip_runtime.h>
#include <stdint.h>

// Problem constants (from reference)
#define NGRAPH 1024
#define DFEAT  256     // D
#define KATOM  64      // atoms per graph
#define KBOND  128     // bonds per graph

typedef __attribute__((ext_vector_type(4))) float accv_t;     // MFMA C/D (4 fp32)
typedef __attribute__((ext_vector_type(8))) short bfrag_t;    // MFMA A/B (8 bf16)
typedef __attribute__((ext_vector_type(4))) unsigned short upk4_t;
typedef __attribute__((ext_vector_type(8))) unsigned short upk8_t;
typedef __attribute__((ext_vector_type(4))) unsigned int u32x4;

__device__ __forceinline__ unsigned short f2bf(float f) {
    union { float f; unsigned int u; } v; v.f = f;
    return (unsigned short)((v.u + 0x7FFFu + ((v.u >> 16) & 1u)) >> 16);
}
__device__ __forceinline__ float sigm(float x) { return 1.0f / (1.0f + __expf(-x)); }
__device__ __forceinline__ float tanh_f(float x) {
    float e = __expf(2.0f * x);
    return 1.0f - 2.0f / (e + 1.0f);
}

// ---------------------------------------------------------------------------
// Streaming fp32 -> int8 quantization with per-node per-32-dim-block scales.
// One wave handles one node per step: lane owns 4 dims (float4); 8-lane
// groups (= 32 dims) reduce max via 3 shfl_xor, quantize, pack 4xint8/u32.
// Non-temporal fp32 loads keep the never-again-read source out of L3.
// grid: 1024 x 256 (4096 waves); atoms 16 nodes/wave, bonds 32.
// ---------------------------------------------------------------------------
__global__ __launch_bounds__(256) void k_cvt(
    const float* __restrict__ fA, const float* __restrict__ fB,
    unsigned int* __restrict__ oA, unsigned int* __restrict__ oB,
    float* __restrict__ scA, float* __restrict__ scB)
{
    int wid  = blockIdx.x * 4 + (threadIdx.x >> 6);   // 0..4095
    int lane = threadIdx.x & 63;
    int grp  = lane >> 3;                             // 32-dim block 0..7

    #pragma unroll 2
    for (int n = wid; n < 65536; n += 4096) {         // atoms
        accv_t v = __builtin_nontemporal_load((const accv_t*)(fA + (size_t)n * 256) + lane);
        float m = fmaxf(fmaxf(fabsf(v[0]), fabsf(v[1])), fmaxf(fabsf(v[2]), fabsf(v[3])));
        m = fmaxf(m, __shfl_xor(m, 1));
        m = fmaxf(m, __shfl_xor(m, 2));
        m = fmaxf(m, __shfl_xor(m, 4));
        float inv = (m > 0.0f) ? 127.0f / m : 0.0f;
        int q0 = (int)rintf(v[0] * inv), q1 = (int)rintf(v[1] * inv);
        int q2 = (int)rintf(v[2] * inv), q3 = (int)rintf(v[3] * inv);
        oA[(size_t)n * 64 + lane] = (unsigned int)(q0 & 0xFF) | ((unsigned int)(q1 & 0xFF) << 8)
                                  | ((unsigned int)(q2 & 0xFF) << 16) | ((unsigned int)(q3 & 0xFF) << 24);
        if ((lane & 7) == 0) scA[(size_t)n * 8 + grp] = m * (1.0f / 127.0f);
    }
    #pragma unroll 2
    for (int n = wid; n < 131072; n += 4096) {        // bonds
        accv_t v = __builtin_nontemporal_load((const accv_t*)(fB + (size_t)n * 256) + lane);
        float m = fmaxf(fmaxf(fabsf(v[0]), fabsf(v[1])), fmaxf(fabsf(v[2]), fabsf(v[3])));
        m = fmaxf(m, __shfl_xor(m, 1));
        m = fmaxf(m, __shfl_xor(m, 2));
        m = fmaxf(m, __shfl_xor(m, 4));
        float inv = (m > 0.0f) ? 127.0f / m : 0.0f;
        int q0 = (int)rintf(v[0] * inv), q1 = (int)rintf(v[1] * inv);
        int q2 = (int)rintf(v[2] * inv), q3 = (int)rintf(v[3] * inv);
        oB[(size_t)n * 64 + lane] = (unsigned int)(q0 & 0xFF) | ((unsigned int)(q1 & 0xFF) << 8)
                                  | ((unsigned int)(q2 & 0xFF) << 16) | ((unsigned int)(q3 & 0xFF) << 24);
        if ((lane & 7) == 0) scB[(size_t)n * 8 + grp] = m * (1.0f / 127.0f);
    }
}

// ---------------------------------------------------------------------------
// Prep: Wc[set][n][k] (bf16), k<256: W_ih[n,k]+W_hh[n,k]; k>=256: W_ih[n,k].
// ---------------------------------------------------------------------------
__global__ __launch_bounds__(512) void k_prep(
    const float* __restrict__ WihA, const float* __restrict__ WhhA,
    const float* __restrict__ bihA, const float* __restrict__ bhhA,
    const float* __restrict__ WihB, const float* __restrict__ WhhB,
    const float* __restrict__ bihB, const float* __restrict__ bhhB,
    unsigned short* __restrict__ Wc, float* __restrict__ bsum)
{
    int bid = blockIdx.x;
    int set = bid >> 10;
    int n   = bid & 1023;
    int k   = threadIdx.x;
    const float* Wih = set ? WihB : WihA;
    const float* Whh = set ? WhhB : WhhA;
    float w = Wih[(size_t)n * 512 + k];
    if (k < 256) w += Whh[(size_t)n * 256 + k];
    Wc[((size_t)(set << 10) + n) * 512 + k] = f2bf(w);
    if (k == 0) {
        const float* bih = set ? bihB : bihA;
        const float* bhh = set ? bhhB : bhhA;
        bsum[(set << 10) + n] = bih[n] + bhh[n];
    }
}

// ---------------------------------------------------------------------------
// LSTM gate GEMM: M=1024, N=1024, K=512 per set. BM=64, BN=128, BK=32,
// 4 waves (32x64 each), 16x16x32 bf16 MFMA. grid: 256 blocks (set = bid>>7).
// ---------------------------------------------------------------------------
__global__ __launch_bounds__(256) void k_gemm(
    const float* __restrict__ hr, const unsigned short* __restrict__ Wc,
    const float* __restrict__ bsum, float* __restrict__ gates)
{
    __shared__ unsigned short sA[64 * 40];
    __shared__ unsigned short sB[128 * 40];

    int set   = blockIdx.x >> 7;
    int qq    = blockIdx.x & 127;
    int mbase = (qq >> 3) * 64;
    int nbase = (qq & 7) * 128;
    int t     = threadIdx.x;
    int lane  = t & 63;
    int w     = t >> 6;
    int wrow  = (w >> 1) * 32;
    int wcol  = (w & 1) * 64;
    int l15   = lane & 15;
    int khalf = (lane >> 4) * 8;

    const float* A           = hr + (size_t)(set << 10) * 512;
    const unsigned short* Bm = Wc + (size_t)(set << 10) * 512;

    accv_t acc[2][4];
    #pragma unroll
    for (int i = 0; i < 2; ++i)
        #pragma unroll
        for (int j = 0; j < 4; ++j)
            acc[i][j] = (accv_t){0.f, 0.f, 0.f, 0.f};

    for (int k0 = 0; k0 < 512; k0 += 32) {
        #pragma unroll
        for (int i = 0; i < 2; ++i) {
            int idx4 = t + 256 * i;
            int row  = idx4 >> 3;
            int kc   = (idx4 & 7) * 4;
            const float4 a = *(const float4*)&A[(size_t)(mbase + row) * 512 + k0 + kc];
            upk4_t u;
            u[0] = f2bf(a.x); u[1] = f2bf(a.y); u[2] = f2bf(a.z); u[3] = f2bf(a.w);
            *(upk4_t*)&sA[row * 40 + kc] = u;
        }
        #pragma unroll
        for (int i = 0; i < 2; ++i) {
            int idx8 = t + 256 * i;
            int row  = idx8 >> 2;
            int kc   = (idx8 & 3) * 8;
            *(upk8_t*)&sB[row * 40 + kc] =
                *(const upk8_t*)&Bm[(size_t)(nbase + row) * 512 + k0 + kc];
        }
        __syncthreads();

        bfrag_t a_f[2], b_f[4];
        #pragma unroll
        for (int i = 0; i < 2; ++i)
            a_f[i] = *(const bfrag_t*)&sA[(wrow + i * 16 + l15) * 40 + khalf];
        #pragma unroll
        for (int j = 0; j < 4; ++j)
            b_f[j] = *(const bfrag_t*)&sB[(wcol + j * 16 + l15) * 40 + khalf];
        #pragma unroll
        for (int i = 0; i < 2; ++i)
            #pragma unroll
            for (int j = 0; j < 4; ++j)
                acc[i][j] = __builtin_amdgcn_mfma_f32_16x16x32_bf16(a_f[i], b_f[j], acc[i][j], 0, 0, 0);
        __syncthreads();
    }

    int r4 = (lane >> 4) * 4;
    #pragma unroll
    for (int i = 0; i < 2; ++i) {
        #pragma unroll
        for (int j = 0; j < 4; ++j) {
            int col  = nbase + wcol + j * 16 + l15;
            float bs = bsum[(set << 10) + col];
            #pragma unroll
            for (int v = 0; v < 4; ++v) {
                int row = mbase + wrow + i * 16 + r4 + v;
                gates[((size_t)(set << 10) + row) * 1024 + col] = acc[i][j][v] + bs;
            }
        }
    }
}

// ---------------------------------------------------------------------------
// Attention, templated on MODE / LAST:
//  MODE 1: read int8 copy + per-32-dim-block scales; MODE 2: fp32 fallback.
//  LAST: write q_star (and feat_global tail) straight to out.
// Structure: 4 waves; lane=(g,s); group g owns nodes wv*npw+4*qd+g; lane s
// owns dims [16s,16s+16) = 1 uint4 (16 int8) + 1 scale per node.
// Pivot softmax (C = first-node logit), reconciled at merge.
// grid: 2048 blocks (0..1023 bonds, 1024..2047 atoms), 256 threads.
// ---------------------------------------------------------------------------
template <int MODE, bool LAST>
__global__ __launch_bounds__(256) void k_attn(
    const float* __restrict__ featA, const float* __restrict__ featB,
    const unsigned int* __restrict__ i8A, const unsigned int* __restrict__ i8B,
    const float* __restrict__ scA, const float* __restrict__ scB,
    const float* __restrict__ gates, const float* __restrict__ bsum,
    float* __restrict__ hr, float* __restrict__ cst,
    const float* __restrict__ fgp, float* __restrict__ outp, int iter)
{
    __shared__ float qv[256];
    __shared__ float sw_s[16], cw_s[16];
    __shared__ float racc_s[16][260];

    int bid = blockIdx.x;
    int set = (bid < 1024) ? 1 : 0;          // bonds first (2x work)
    int b   = bid & 1023;
    int K   = set ? KBOND : KATOM;
    int t = threadIdx.x;
    size_t sb = (size_t)(set << 10) + b;
    size_t ob = (size_t)b * 1152 + (set ? 512 : 0);

    // ---- stage 1: LSTM elementwise, d = t ----
    {
        int d = t;
        float gi, gf, gg, go, cold;
        if (iter == 0) {
            gi = bsum[(set << 10) + d];
            gf = bsum[(set << 10) + 256 + d];
            gg = bsum[(set << 10) + 512 + d];
            go = bsum[(set << 10) + 768 + d];
            cold = 0.0f;
        } else {
            const float* gp = gates + sb * 1024;
            gi = gp[d]; gf = gp[256 + d]; gg = gp[512 + d]; go = gp[768 + d];
            cold = cst[sb * 256 + d];
        }
        float cn = sigm(gf) * cold + sigm(gi) * tanh_f(gg);
        float h  = sigm(go) * tanh_f(cn);
        if (LAST) { outp[ob + d] = h; }
        else      { cst[sb * 256 + d] = cn; hr[sb * 512 + d] = h; }
        qv[d] = h;
    }
    __syncthreads();

    int lane = t & 63;
    int wv   = t >> 6;
    int g    = lane >> 4;
    int s    = lane & 15;
    int npw  = K >> 2;
    int nq   = npw >> 2;
    int node0 = wv * npw + g;
    float C = 0.0f, sacc = 0.0f;
    int pid = (wv << 2) | g;

    if (MODE == 1) {
        // int8 read path: per node 1 uint4 (16 int8, dims 16s..16s+16) + scale
        const unsigned int* fb = (set ? i8B : i8A)
                               + ((size_t)b * K + node0) * 64 + s * 4;
        const float* scp = (set ? scB : scA)
                         + ((size_t)b * K + node0) * 8 + (s >> 1);

        float qr[16];
        #pragma unroll
        for (int j = 0; j < 16; ++j) qr[j] = qv[s * 16 + j];
        float r[16];
        #pragma unroll
        for (int j = 0; j < 16; ++j) r[j] = 0.0f;

        #pragma unroll 4
        for (int qd = 0; qd < nq; ++qd) {
            u32x4 hx = *(const u32x4*)(fb + (size_t)qd * 256);
            float sc = scp[(size_t)qd * 32];
            float x[16];
            #pragma unroll
            for (int w4 = 0; w4 < 4; ++w4) {
                unsigned int u = hx[w4];
                x[w4 * 4 + 0] = (float)((int)(u << 24) >> 24);
                x[w4 * 4 + 1] = (float)((int)(u << 16) >> 24);
                x[w4 * 4 + 2] = (float)((int)(u << 8)  >> 24);
                x[w4 * 4 + 3] = (float)((int)u >> 24);
            }
            float e = 0.0f;
            #pragma unroll
            for (int j = 0; j < 16; ++j) e += x[j] * qr[j];
            e *= sc;                      // fold this lane's block scale
            e += __shfl_xor(e, 1);
            e += __shfl_xor(e, 2);
            e += __shfl_xor(e, 4);
            e += __shfl_xor(e, 8);
            float w = (qd == 0) ? 1.0f : __expf(e - C);
            if (qd == 0) C = e;
            sacc += w;
            float wl = w * sc;            // scale folded into readout weight
            #pragma unroll
            for (int j = 0; j < 16; ++j) r[j] += wl * x[j];
        }
        #pragma unroll
        for (int j = 0; j < 16; j += 4)
            *(float4*)&racc_s[pid][s * 16 + j] = *(float4*)&r[j];
    } else {
        // fp32 fallback: lane owns dims {c*64 + s*4..+4}, c=0..3
        const float* feat = set ? featB : featA;
        const float* fb = feat + ((size_t)b * K + node0) * 256 + s * 4;
        float4 q0 = *(const float4*)&qv[s*4];
        float4 q1 = *(const float4*)&qv[64  + s*4];
        float4 q2 = *(const float4*)&qv[128 + s*4];
        float4 q3 = *(const float4*)&qv[192 + s*4];
        float4 r0 = make_float4(0.f,0.f,0.f,0.f), r1 = r0, r2 = r0, r3 = r0;
        #pragma unroll 2
        for (int qd = 0; qd < nq; ++qd) {
            const float* p = fb + (size_t)qd * 1024;
            float4 x0 = *(const float4*)(p);
            float4 x1 = *(const float4*)(p + 64);
            float4 x2 = *(const float4*)(p + 128);
            float4 x3 = *(const float4*)(p + 192);
            float e = x0.x*q0.x + x0.y*q0.y + x0.z*q0.z + x0.w*q0.w
                    + x1.x*q1.x + x1.y*q1.y + x1.z*q1.z + x1.w*q1.w
                    + x2.x*q2.x + x2.y*q2.y + x2.z*q2.z + x2.w*q2.w
                    + x3.x*q3.x + x3.y*q3.y + x3.z*q3.z + x3.w*q3.w;
            e += __shfl_xor(e, 1); e += __shfl_xor(e, 2);
            e += __shfl_xor(e, 4); e += __shfl_xor(e, 8);
            float w = (qd == 0) ? 1.0f : __expf(e - C);
            if (qd == 0) C = e;
            sacc += w;
            r0.x += w*x0.x; r0.y += w*x0.y; r0.z += w*x0.z; r0.w += w*x0.w;
            r1.x += w*x1.x; r1.y += w*x1.y; r1.z += w*x1.z; r1.w += w*x1.w;
            r2.x += w*x2.x; r2.y += w*x2.y; r2.z += w*x2.z; r2.w += w*x2.w;
            r3.x += w*x3.x; r3.y += w*x3.y; r3.z += w*x3.z; r3.w += w*x3.w;
        }
        *(float4*)&racc_s[pid][s*4]       = r0;
        *(float4*)&racc_s[pid][64  + s*4] = r1;
        *(float4*)&racc_s[pid][128 + s*4] = r2;
        *(float4*)&racc_s[pid][192 + s*4] = r3;
    }
    if (s == 0) { sw_s[pid] = sacc; cw_s[pid] = C; }
    __syncthreads();

    // ---- stage 3: pivot-reconciled merge of 16 partials, d = t ----
    {
        float Cm = cw_s[0];
        #pragma unroll
        for (int p2 = 1; p2 < 16; ++p2) Cm = fmaxf(Cm, cw_s[p2]);
        float S = 0.0f, r = 0.0f;
        #pragma unroll
        for (int p2 = 0; p2 < 16; ++p2) {
            float f = __expf(cw_s[p2] - Cm);
            S += sw_s[p2] * f;
            r += racc_s[p2][t] * f;
        }
        float rv = r / S;
        if (LAST) {
            outp[ob + 256 + t] = rv;
            if (set && t < 128)
                outp[(size_t)b * 1152 + 1024 + t] = fgp[(size_t)b * 128 + t];
        } else {
            hr[sb * 512 + 256 + t] = rv;
        }
    }
}

// ---------------------------------------------------------------------------
// Final concat (fp32 fallback path only).
// ---------------------------------------------------------------------------
__global__ __launch_bounds__(288) void k_out(
    const float* __restrict__ hr, const float* __restrict__ fg,
    float* __restrict__ out)
{
    int b  = blockIdx.x;
    int c4 = threadIdx.x * 4;
    float4 v;
    if (c4 < 512)       v = *(const float4*)&hr[(size_t)b * 512 + c4];
    else if (c4 < 1024) v = *(const float4*)&hr[(size_t)(1024 + b) * 512 + (c4 - 512)];
    else                v = *(const float4*)&fg[(size_t)b * 128 + (c4 - 1024)];
    *(float4*)&out[(size_t)b * 1152 + c4] = v;
}

extern "C" void kernel_launch(void* const* d_in, const int* in_sizes, int n_in,
                              void* d_out, int out_size, void* d_ws, size_t ws_size,
                              hipStream_t stream) {
    const float* feat_atom   = (const float*)d_in[0];
    const float* feat_bond   = (const float*)d_in[2];
    const float* feat_global = (const float*)d_in[4];
    const float* WihA = (const float*)d_in[5];
    const float* WhhA = (const float*)d_in[6];
    const float* bihA = (const float*)d_in[7];
    const float* bhhA = (const float*)d_in[8];
    const float* WihB = (const float*)d_in[9];
    const float* WhhB = (const float*)d_in[10];
    const float* bihB = (const float*)d_in[11];
    const float* bhhB = (const float*)d_in[12];
    float* out = (float*)d_out;

    // workspace layout (bytes)
    char* ws = (char*)d_ws;
    unsigned short* Wc = (unsigned short*)(ws + 0);           // 2,097,152
    float* bsum  = (float*)(ws + 2097152);                    // 8,192
    float* gates = (float*)(ws + 2105344);                    // 8,388,608
    float* hr    = (float*)(ws + 10493952);                   // 4,194,304
    float* cst   = (float*)(ws + 14688256);                   // 2,097,152
    unsigned int* i8A = (unsigned int*)(ws + 16785408);       // 16,777,216
    unsigned int* i8B = (unsigned int*)(ws + 33562624);       // 33,554,432
    float* scA = (float*)(ws + 67117056);                     // 2,097,152
    float* scB = (float*)(ws + 69214208);                     // 4,194,304
    const size_t WS_NEED = 69214208 + 4194304;                // 73,408,512
    (void)in_sizes; (void)n_in; (void)out_size;

    bool i8 = (ws_size >= WS_NEED);

    k_prep<<<2048, 512, 0, stream>>>(WihA, WhhA, bihA, bhhA,
                                     WihB, WhhB, bihB, bhhB, Wc, bsum);
    if (i8) {
        k_cvt<<<1024, 256, 0, stream>>>(feat_atom, feat_bond, i8A, i8B, scA, scB);
        k_attn<1, false><<<2048, 256, 0, stream>>>(feat_atom, feat_bond, i8A, i8B,
                                                   scA, scB, gates, bsum, hr, cst,
                                                   feat_global, out, 0);
        for (int it = 1; it < 5; ++it) {
            k_gemm<<<256, 256, 0, stream>>>(hr, Wc, bsum, gates);
            k_attn<1, false><<<2048, 256, 0, stream>>>(feat_atom, feat_bond, i8A, i8B,
                                                       scA, scB, gates, bsum, hr, cst,
                                                       feat_global, out, it);
        }
        k_gemm<<<256, 256, 0, stream>>>(hr, Wc, bsum, gates);
        k_attn<1, true><<<2048, 256, 0, stream>>>(feat_atom, feat_bond, i8A, i8B,
                                                  scA, scB, gates, bsum, hr, cst,
                                                  feat_global, out, 5);
    } else {
        k_attn<2, false><<<2048, 256, 0, stream>>>(feat_atom, feat_bond, 0, 0, 0, 0,
                                                   gates, bsum, hr, cst,
                                                   feat_global, out, 0);
        for (int it = 1; it < 6; ++it) {
            k_gemm<<<256, 256, 0, stream>>>(hr, Wc, bsum, gates);
            k_attn<2, false><<<2048, 256, 0, stream>>>(feat_atom, feat_bond, 0, 0, 0, 0,
                                                       gates, bsum, hr, cst,
                                                       feat_global, out, it);
        }
        k_out<<<1024, 288, 0, stream>>>(hr, feat_global, out);
    }
}